// Round 7
// baseline (74.092 us; speedup 1.0000x reference)
//
#include <hip/hip_runtime.h>
#include <math.h>

#define M_WAVE 32
#define NLEN 8192
#define FFT_N 16384
#define THREADS 1024
#define NPAIR 528   // 496 cross (blocks 0..495) + 32 autos (blocks 496..527)

#define TWOPI_F 6.28318530717958647692f

__device__ __forceinline__ float2 cadd(float2 a, float2 b){return make_float2(a.x+b.x, a.y+b.y);}
__device__ __forceinline__ float2 csub(float2 a, float2 b){return make_float2(a.x-b.x, a.y-b.y);}
__device__ __forceinline__ float2 cmul(float2 a, float2 b){return make_float2(a.x*b.x-a.y*b.y, a.x*b.y+a.y*b.x);}
__device__ __forceinline__ float2 mul_i (float2 a){return make_float2(-a.y,  a.x);}
__device__ __forceinline__ float2 mul_mi(float2 a){return make_float2( a.y, -a.x);}

__device__ __forceinline__ float2 dpp_xor1(float2 v){
    float2 r;
    r.x = __int_as_float(__builtin_amdgcn_mov_dpp(__float_as_int(v.x), 0xB1, 0xF, 0xF, true));
    r.y = __int_as_float(__builtin_amdgcn_mov_dpp(__float_as_int(v.y), 0xB1, 0xF, 0xF, true));
    return r;
}
__device__ __forceinline__ float2 dpp_xor2(float2 v){
    float2 r;
    r.x = __int_as_float(__builtin_amdgcn_mov_dpp(__float_as_int(v.x), 0x4E, 0xF, 0xF, true));
    r.y = __int_as_float(__builtin_amdgcn_mov_dpp(__float_as_int(v.y), 0x4E, 0xF, 0xF, true));
    return r;
}

__device__ __forceinline__ float waveReduceMax(float v) {
    #pragma unroll
    for (int off = 32; off > 0; off >>= 1) v = fmaxf(v, __shfl_down(v, off, 64));
    return v;
}
__device__ __forceinline__ float waveReduceSum(float v) {
    #pragma unroll
    for (int off = 32; off > 0; off >>= 1) v += __shfl_down(v, off, 64);
    return v;
}

// second half of the 16-pt DFT (twiddle + second radix-4 pass), shared
template<int SGN>
__device__ __forceinline__ void dft16_tail(float2 w[16], float2 v[16]){
    const float C1 = 0.923879532511286756f;
    const float S1 = 0.382683432365089772f;
    const float R2 = 0.707106781186547524f;
    const float G = (SGN < 0) ? -1.0f : 1.0f;
    w[5]  = cmul(w[5],  make_float2( C1,  G*S1));
    w[6]  = cmul(w[6],  make_float2( R2,  G*R2));
    w[7]  = cmul(w[7],  make_float2( S1,  G*C1));
    w[9]  = cmul(w[9],  make_float2( R2,  G*R2));
    w[10] = (SGN<0) ? mul_mi(w[10]) : mul_i(w[10]);
    w[11] = cmul(w[11], make_float2(-R2,  G*R2));
    w[13] = cmul(w[13], make_float2( S1,  G*C1));
    w[14] = cmul(w[14], make_float2(-R2,  G*R2));
    w[15] = cmul(w[15], make_float2(-C1, -G*S1));
    #pragma unroll
    for (int k0 = 0; k0 < 4; ++k0){
        float2 a = w[k0*4+0], b = w[k0*4+1], c = w[k0*4+2], d = w[k0*4+3];
        float2 t0 = cadd(a,c), t1 = csub(a,c), t2 = cadd(b,d), t3 = csub(b,d);
        float2 j3 = (SGN < 0) ? mul_mi(t3) : mul_i(t3);
        v[k0]    = cadd(t0,t2);
        v[k0+4]  = cadd(t1,j3);
        v[k0+8]  = csub(t0,t2);
        v[k0+12] = csub(t1,j3);
    }
}

template<int SGN>
__device__ __forceinline__ void dft16(float2 v[16]){
    float2 w[16];
    #pragma unroll
    for (int n0 = 0; n0 < 4; ++n0){
        float2 a = v[n0], b = v[n0+4], c = v[n0+8], d = v[n0+12];
        float2 t0 = cadd(a,c), t1 = csub(a,c), t2 = cadd(b,d), t3 = csub(b,d);
        float2 j3 = (SGN < 0) ? mul_mi(t3) : mul_i(t3);
        w[n0]    = cadd(t0,t2);
        w[4+n0]  = cadd(t1,j3);
        w[8+n0]  = csub(t0,t2);
        w[12+n0] = csub(t1,j3);
    }
    dft16_tail<SGN>(w, v);
}

// forward DFT16 with inputs 8..15 == 0 (zero-padded), SGN=-1
__device__ __forceinline__ void dft16_zero8(float2 v[16]){
    float2 w[16];
    #pragma unroll
    for (int n0 = 0; n0 < 4; ++n0){
        float2 a = v[n0], b = v[n0+4];
        w[n0]    = cadd(a,b);
        w[4+n0]  = make_float2(a.x + b.y, a.y - b.x);  // a - i b
        w[8+n0]  = csub(a,b);
        w[12+n0] = make_float2(a.x - b.y, a.y + b.x);  // a + i b
    }
    dft16_tail<-1>(w, v);
}

template<int SGN>
__device__ __forceinline__ void twchain16(float2 v[16], float theta){
    float th = (SGN < 0) ? -theta : theta;
    float s1,c1; __sincosf(th, &s1, &c1);
    float s4,c4; __sincosf(4.0f*th, &s4, &c4);
    float2 w1 = make_float2(c1,s1), w4 = make_float2(c4,s4);
    float2 lo2 = cmul(w1,w1), lo3 = cmul(lo2,w1);
    float2 hi2 = cmul(w4,w4), hi3 = cmul(hi2,w4);
    float2 lo[4] = {make_float2(1.f,0.f), w1, lo2, lo3};
    float2 hi[4] = {make_float2(1.f,0.f), w4, hi2, hi3};
    #pragma unroll
    for (int s = 1; s < 16; ++s){
        v[s] = cmul(v[s], cmul(hi[s>>2], lo[s&3]));
    }
}

// v[s] *= e^{+i(phi0 + s*theta)}  (offset version, includes s=0)
__device__ __forceinline__ void twchain16_o(float2 v[16], float theta, float phi0){
    float s0,c0; __sincosf(phi0, &s0, &c0);
    float s1,c1; __sincosf(theta, &s1, &c1);
    float s4,c4; __sincosf(4.0f*theta, &s4, &c4);
    float2 W0 = make_float2(c0,s0), w1 = make_float2(c1,s1), w4 = make_float2(c4,s4);
    float2 lo2 = cmul(w1,w1), lo3 = cmul(lo2,w1);
    float2 hi1 = cmul(W0,w4), hi2 = cmul(hi1,w4), hi3 = cmul(hi2,w4);
    float2 lo[4] = {make_float2(1.f,0.f), w1, lo2, lo3};
    float2 hi[4] = {W0, hi1, hi2, hi3};
    #pragma unroll
    for (int s = 0; s < 16; ++s){
        v[s] = cmul(v[s], cmul(hi[s>>2], lo[s&3]));
    }
}

__device__ __forceinline__ int L1swz(int e){
    return (e & ~63) | (((e & 63) + ((e >> 6) & 15)) & 63);
}

// Forward FFT: network identical to R4/R6 (verified); only the final store map
// changed: element with freq digits k = a + 16b + 256c + 4096d is stored at
// p = 16a + 256b + 4096(c&3) + (c>>2) + 4d, so pair loads are contiguous.
__global__ __launch_bounds__(256, 1) void fwd_fft_kernel(const float* __restrict__ x,
                                                         float2* __restrict__ spec) {
    __shared__ float2 X4[4096];  // 32 KiB
    const int bx = blockIdx.x, m = bx >> 2, qt = bx & 3;
    const int tid = threadIdx.x;

    #pragma unroll 1
    for (int cc = 0; cc < 4; ++cc){
        const int j = cc*256 + tid;
        float2 v[16];
        #pragma unroll
        for (int s = 0; s < 8; ++s){
            float ph = TWOPI_F * x[m*NLEN + s*1024 + j];
            float sn,cs; __sincosf(ph,&sn,&cs);
            v[s] = make_float2(cs,sn);
        }
        dft16_zero8(v);
        const float th = TWOPI_F * (float)j / 16384.0f;
        float sb,cb; __sincosf(-(float)(4*qt)*th, &sb, &cb);
        float ss,cs2; __sincosf(-th, &ss, &cs2);
        float2 wcur = make_float2(cb,sb), wstep = make_float2(cs2,ss);
        #pragma unroll
        for (int d = 0; d < 4; ++d){
            X4[d*1024 + L1swz(j)] = cmul(v[4*qt + d], wcur);
            wcur = cmul(wcur, wstep);
        }
    }
    __syncthreads();

    const int wv = tid >> 6, jB = tid & 63;
    float2 v[16];
    #pragma unroll
    for (int t = 0; t < 16; ++t) v[t] = X4[wv*1024 + t*64 + ((jB + t) & 63)];
    dft16<-1>(v);
    twchain16<-1>(v, TWOPI_F * (float)jB / 1024.0f);
    #pragma unroll
    for (int sp = 0; sp < 16; ++sp) X4[wv*1024 + sp*64 + ((jB + 4*sp) & 63)] = v[sp];
    // no barrier: stage C reads only this wave's chunk

    {
        const int bl = (tid & 63) >> 2, jC = tid & 3;
        #pragma unroll
        for (int a = 0; a < 16; ++a)
            v[a] = X4[wv*1024 + bl*64 + ((4*a + jC + 4*bl) & 63)];
        dft16<-1>(v);
        twchain16<-1>(v, TWOPI_F * (float)jC / 64.0f);
        const bool odd1 = (jC & 1) != 0;
        const bool odd2 = (jC & 2) != 0;
        #pragma unroll
        for (int e = 0; e < 16; ++e){
            float2 p = dpp_xor2(v[e]);
            float2 t = odd2 ? csub(p, v[e]) : cadd(v[e], p);
            float2 q = dpp_xor1(t);
            float2 re = odd1 ? csub(q, t) : cadd(t, q);
            float2 ro = odd1 ? cadd(q, mul_i(t)) : cadd(t, mul_mi(q));
            v[e] = odd2 ? ro : re;
        }
        const int u = ((jC & 1) << 1) | (jC >> 1);    // this lane's d-digit
        const int a_dig = 4*qt + wv;                  // chunk = low freq digit
        float2* dstp = spec + (size_t)m*FFT_N;
        const int base0 = 16*a_dig + 256*bl + 4*u;
        #pragma unroll
        for (int r4 = 0; r4 < 4; ++r4){
            const int base = base0 + 4096*r4;
            *(float4*)(dstp + base)     = make_float4(v[r4].x,    v[r4].y,    v[r4+4].x,  v[r4+4].y);
            *(float4*)(dstp + base + 2) = make_float4(v[r4+8].x,  v[r4+8].y,  v[r4+12].x, v[r4+12].y);
        }
    }
}

// Pair kernel, restructured: in-thread radix-4 (k4) + three radix-16 stages with
// LDS digit transposes (T1, T2 cross-wave; T3 wave-local). No DPP stage.
// Thread tid = k1 + 16*k2 + 256*q; loads spec[tid*16 + e], e = k3H + 4*k4.
__global__ __launch_bounds__(THREADS, 4) void pair_kernel(const float2* __restrict__ spec,
                                                          float4* __restrict__ rec) {
    __shared__ float2 X[FFT_N];  // used as 64 rows x 256 cols (float2)
    const int r = blockIdx.x, tid = threadIdx.x;
    const bool is_auto = (r >= 496);
    int a, b, rec_idx;
    if (is_auto){
        a = b = r - 496;
        rec_idx = r - 496;           // autos -> rec[0..31]
    } else {
        int t = r; a = 0; int rem = M_WAVE - 1;
        while (t >= rem){ t -= rem; ++a; rem = M_WAVE - 1 - a; }
        b = a + 1 + t;
        rec_idx = M_WAVE + r;        // cross -> rec[32..527]
    }
    const int q   = tid >> 8;         // k3 low 2 bits
    const int k2  = (tid >> 4) & 15;
    const int col = tid & 255;        // k1 + 16*k2
    float2 v[16];

    // Load both spectra: 128 B contiguous per thread, product B*conj(A)
    {
        const float4* pa = (const float4*)(spec + (size_t)a*FFT_N + (size_t)tid*16);
        const float4* pb = (const float4*)(spec + (size_t)b*FFT_N + (size_t)tid*16);
        #pragma unroll
        for (int e = 0; e < 8; ++e){
            float4 A = pa[e], B = pb[e];
            v[2*e]   = make_float2(B.x*A.x + B.y*A.y, B.y*A.x - B.x*A.y);
            v[2*e+1] = make_float2(B.z*A.z + B.w*A.w, B.w*A.z - B.z*A.w);
        }
    }
    // Stage 1: radix-4 over k4 (elements g, g+4, g+8, g+12), inverse (+i)
    #pragma unroll
    for (int g = 0; g < 4; ++g){
        float2 aa=v[g], bb=v[g+4], cc=v[g+8], dd=v[g+12];
        float2 t0=cadd(aa,cc), t1=csub(aa,cc), t2=cadd(bb,dd), t3=csub(bb,dd);
        float2 it3 = mul_i(t3);
        v[g]    = cadd(t0,t2);
        v[g+4]  = cadd(t1,it3);
        v[g+8]  = csub(t0,t2);
        v[g+12] = csub(t1,it3);
        // twiddle W64^{+n4*k3}, k3 = q + 4g
        float th = (TWOPI_F/64.0f) * (float)(q + 4*g);
        float sn,cs; __sincosf(th,&sn,&cs);
        float2 w1 = make_float2(cs,sn), w2 = cmul(w1,w1), w3 = cmul(w2,w1);
        v[g+4]  = cmul(v[g+4],  w1);
        v[g+8]  = cmul(v[g+8],  w2);
        v[g+12] = cmul(v[g+12], w3);
    }
    // T1 write: slot i = g + 4*n4 -> row = q*16 + 4*(i&3) + (i>>2)
    #pragma unroll
    for (int i = 0; i < 16; ++i)
        X[(q*16 + 4*(i&3) + (i>>2))*256 + col] = v[i];
    __syncthreads();
    // T1 read: v[k3], row = 16*(k3&3) + 4*(k3>>2) + q
    #pragma unroll
    for (int k3 = 0; k3 < 16; ++k3)
        v[k3] = X[(16*(k3&3) + 4*((k3>>2)&3) + q)*256 + col];
    dft16<+1>(v);   // over k3 -> v[n3]
    // twiddle W1024^{+(q+4n3)*k2}
    twchain16_o(v, (TWOPI_F*4.0f/1024.0f)*(float)k2, (TWOPI_F/1024.0f)*(float)(q*k2));
    __syncthreads();   // all T1 reads done before T2 writes
    // T2 write: row = q*16 + n3
    #pragma unroll
    for (int n3 = 0; n3 < 16; ++n3)
        X[(q*16 + n3)*256 + col] = v[n3];
    __syncthreads();
    // T2 read: v[k2'] from row = q*16 + k2_own, col = k1 + 16*k2'
    {
        const int rowB = (q*16 + k2)*256 + (tid & 15);
        #pragma unroll
        for (int k2p = 0; k2p < 16; ++k2p)
            v[k2p] = X[rowB + 16*k2p];
    }
    dft16<+1>(v);   // over k2 -> v[n2]
    __syncthreads();   // all T2 reads done before T3 writes
    // T3 (wave-local, lane&15 exchange): write row = q*16+n2, col = (col+n2)&255
    #pragma unroll
    for (int n2 = 0; n2 < 16; ++n2)
        X[(q*16 + n2)*256 + ((col + n2) & 255)] = v[n2];
    {
        const int s = tid & 15;
        const int rbase = (q*16 + s)*256;
        const int cbase = (tid & 240) + s;
        #pragma unroll
        for (int k1p = 0; k1p < 16; ++k1p)
            v[k1p] = X[rbase + ((cbase + k1p) & 255)];
    }
    // final twiddle + DFT16 over k1: base = q + 4r + 64s
    const int base_n = q + 4*((tid>>4)&15) + 64*(tid&15);
    twchain16<+1>(v, TWOPI_F * (float)base_n / 16384.0f);
    dft16<+1>(v);   // v[n1] = 16384 * sigma[n1*1024 + base_n]

    // Stats (unchanged; lag = t*1024 + base_n, base_n==0 <=> tid==0)
    const float CSCALE = 0.1f / (16384.0f * 16384.0f);
    const bool j0 = (tid == 0);
    float uval[16];
    float lm = 0.f, lsum = 0.f;
    #pragma unroll
    for (int t = 0; t < 16; ++t){
        float uu = CSCALE * (v[t].x*v[t].x + v[t].y*v[t].y);
        uval[t] = uu;
        if (is_auto){
            bool valid = (t > 8) || ((t == 8) && !j0);
            if (valid){ lm = fmaxf(lm, uu); lsum += uu; }
        } else {
            bool inv = (t == 8) && j0;
            if (!inv){ lm = fmaxf(lm, uu); lsum += uu; }
            if (t == 0 && j0) lsum += uu;
        }
    }
    __syncthreads();  // X reads done; reuse as scratch

    float* scratch = (float*)X;
    const int lane = tid & 63, wvv = tid >> 6;
    float wm = waveReduceMax(lm);
    float wsm = waveReduceSum(lsum);
    if (lane == 0){ scratch[wvv] = wm; scratch[16+wvv] = wsm; }
    __syncthreads();
    float m_b = scratch[0], sumu = scratch[16];
    #pragma unroll
    for (int i = 1; i < 16; ++i){ m_b = fmaxf(m_b, scratch[i]); sumu += scratch[16+i]; }

    const float invTN2 = 1.0f / 67108.864f;   // 1/(T*N*N)
    float le = 0.f;
    #pragma unroll
    for (int t = 0; t < 16; ++t){
        float ex = __expf((uval[t] - m_b) * invTN2);
        if (is_auto){
            bool valid = (t > 8) || ((t == 8) && !j0);
            if (valid) le += ex;
        } else {
            bool inv = (t == 8) && j0;
            if (!inv) le += ((t == 0 && j0) ? 2.f : 1.f) * ex;
        }
    }
    float wle = waveReduceSum(le);
    if (lane == 0) scratch[32+wvv] = wle;
    __syncthreads();
    if (tid == 0){
        float sb2 = 0.f;
        #pragma unroll
        for (int i = 0; i < 16; ++i) sb2 += scratch[32+i];
        rec[rec_idx] = make_float4(m_b, sumu, sb2, 0.f);
    }
}

// Merge 528 records -> 7 outputs. Autos at rec[0..31], cross at rec[32..527].
__global__ __launch_bounds__(256) void final_kernel(const float4* __restrict__ rec,
                                                    float* __restrict__ out) {
    __shared__ float smA[256], smC[256];
    __shared__ double sS[256], sA[256], sC[256];
    const int tid = threadIdx.x;

    float mA = 0.f, mC = 0.f;
    for (int r = tid; r < NPAIR; r += 256){
        float mx = rec[r].x;
        if (r < M_WAVE) mA = fmaxf(mA, mx); else mC = fmaxf(mC, mx);
    }
    smA[tid] = mA; smC[tid] = mC;
    __syncthreads();
    for (int s = 128; s > 0; s >>= 1){
        if (tid < s){ smA[tid]=fmaxf(smA[tid],smA[tid+s]); smC[tid]=fmaxf(smC[tid],smC[tid+s]); }
        __syncthreads();
    }
    const float maxA_g = smA[0], maxC_g = smC[0];
    const float Mall = fmaxf(maxA_g, maxC_g);

    const float invTN2f = 1.0f / 67108.864f;
    double S = 0.0, sumA = 0.0, sumC = 0.0;
    for (int r = tid; r < NPAIR; r += 256){
        float4 rv = rec[r];
        S += (double)rv.z * (double)__expf((rv.x - Mall)*invTN2f);
        if (r < M_WAVE) sumA += (double)rv.y; else sumC += (double)rv.y;
    }
    sS[tid]=S; sA[tid]=sumA; sC[tid]=sumC;
    __syncthreads();
    for (int s = 128; s > 0; s >>= 1){
        if (tid < s){ sS[tid]+=sS[tid+s]; sA[tid]+=sA[tid+s]; sC[tid]+=sC[tid+s]; }
        __syncthreads();
    }
    if (tid == 0){
        const double invN2 = 1.0/67108864.0;
        out[0] = (float)((double)Mall*invN2 + 1e-3*log(sS[0]));
        out[1] = (float)((double)Mall*invN2);
        out[2] = maxA_g;
        out[3] = maxC_g;
        out[4] = (float)((sA[0]+sC[0])*invN2);
        out[5] = (float)sA[0];
        out[6] = (float)sC[0];
    }
}

extern "C" void kernel_launch(void* const* d_in, const int* in_sizes, int n_in,
                              void* d_out, int out_size, void* d_ws, size_t ws_size,
                              hipStream_t stream) {
    (void)in_sizes; (void)n_in; (void)out_size; (void)ws_size;
    const float* x = (const float*)d_in[0];
    float* out = (float*)d_out;

    float2* spec = (float2*)d_ws;
    float4* rec = (float4*)((char*)d_ws + (size_t)M_WAVE * FFT_N * sizeof(float2));

    fwd_fft_kernel<<<128, 256, 0, stream>>>(x, spec);
    pair_kernel<<<NPAIR, THREADS, 0, stream>>>(spec, rec);
    final_kernel<<<1, 256, 0, stream>>>(rec, out);
}

// Round 8
// 61.071 us; speedup vs baseline: 1.2132x; 1.2132x over previous
//
#include <hip/hip_runtime.h>
#include <math.h>

#define M_WAVE 32
#define NLEN 8192
#define FFT_N 16384
#define THREADS 1024
#define NPAIR 528   // 496 cross (blocks 0..495) + 32 autos (blocks 496..527)

#define TWOPI_F 6.28318530717958647692f

__device__ __forceinline__ float2 cadd(float2 a, float2 b){return make_float2(a.x+b.x, a.y+b.y);}
__device__ __forceinline__ float2 csub(float2 a, float2 b){return make_float2(a.x-b.x, a.y-b.y);}
__device__ __forceinline__ float2 cmul(float2 a, float2 b){return make_float2(a.x*b.x-a.y*b.y, a.x*b.y+a.y*b.x);}
__device__ __forceinline__ float2 mul_i (float2 a){return make_float2(-a.y,  a.x);}
__device__ __forceinline__ float2 mul_mi(float2 a){return make_float2( a.y, -a.x);}

// bf16x2 pack/unpack: one complex float2 <-> one u32 (re=low16, im=high16)
__device__ __forceinline__ unsigned pkc(float2 v){
    unsigned r;
    asm("v_cvt_pk_bf16_f32 %0, %1, %2" : "=v"(r) : "v"(v.x), "v"(v.y));
    return r;
}
__device__ __forceinline__ float2 upkc(unsigned u){
    return make_float2(__uint_as_float(u << 16), __uint_as_float(u & 0xFFFF0000u));
}

__device__ __forceinline__ float2 dpp_xor1(float2 v){
    float2 r;
    r.x = __int_as_float(__builtin_amdgcn_mov_dpp(__float_as_int(v.x), 0xB1, 0xF, 0xF, true));
    r.y = __int_as_float(__builtin_amdgcn_mov_dpp(__float_as_int(v.y), 0xB1, 0xF, 0xF, true));
    return r;
}
__device__ __forceinline__ float2 dpp_xor2(float2 v){
    float2 r;
    r.x = __int_as_float(__builtin_amdgcn_mov_dpp(__float_as_int(v.x), 0x4E, 0xF, 0xF, true));
    r.y = __int_as_float(__builtin_amdgcn_mov_dpp(__float_as_int(v.y), 0x4E, 0xF, 0xF, true));
    return r;
}

__device__ __forceinline__ float waveReduceMax(float v) {
    #pragma unroll
    for (int off = 32; off > 0; off >>= 1) v = fmaxf(v, __shfl_down(v, off, 64));
    return v;
}
__device__ __forceinline__ float waveReduceSum(float v) {
    #pragma unroll
    for (int off = 32; off > 0; off >>= 1) v += __shfl_down(v, off, 64);
    return v;
}

// second half of the 16-pt DFT (twiddle + second radix-4 pass), shared
template<int SGN>
__device__ __forceinline__ void dft16_tail(float2 w[16], float2 v[16]){
    const float C1 = 0.923879532511286756f;
    const float S1 = 0.382683432365089772f;
    const float R2 = 0.707106781186547524f;
    const float G = (SGN < 0) ? -1.0f : 1.0f;
    w[5]  = cmul(w[5],  make_float2( C1,  G*S1));
    w[6]  = cmul(w[6],  make_float2( R2,  G*R2));
    w[7]  = cmul(w[7],  make_float2( S1,  G*C1));
    w[9]  = cmul(w[9],  make_float2( R2,  G*R2));
    w[10] = (SGN<0) ? mul_mi(w[10]) : mul_i(w[10]);
    w[11] = cmul(w[11], make_float2(-R2,  G*R2));
    w[13] = cmul(w[13], make_float2( S1,  G*C1));
    w[14] = cmul(w[14], make_float2(-R2,  G*R2));
    w[15] = cmul(w[15], make_float2(-C1, -G*S1));
    #pragma unroll
    for (int k0 = 0; k0 < 4; ++k0){
        float2 a = w[k0*4+0], b = w[k0*4+1], c = w[k0*4+2], d = w[k0*4+3];
        float2 t0 = cadd(a,c), t1 = csub(a,c), t2 = cadd(b,d), t3 = csub(b,d);
        float2 j3 = (SGN < 0) ? mul_mi(t3) : mul_i(t3);
        v[k0]    = cadd(t0,t2);
        v[k0+4]  = cadd(t1,j3);
        v[k0+8]  = csub(t0,t2);
        v[k0+12] = csub(t1,j3);
    }
}

template<int SGN>
__device__ __forceinline__ void dft16(float2 v[16]){
    float2 w[16];
    #pragma unroll
    for (int n0 = 0; n0 < 4; ++n0){
        float2 a = v[n0], b = v[n0+4], c = v[n0+8], d = v[n0+12];
        float2 t0 = cadd(a,c), t1 = csub(a,c), t2 = cadd(b,d), t3 = csub(b,d);
        float2 j3 = (SGN < 0) ? mul_mi(t3) : mul_i(t3);
        w[n0]    = cadd(t0,t2);
        w[4+n0]  = cadd(t1,j3);
        w[8+n0]  = csub(t0,t2);
        w[12+n0] = csub(t1,j3);
    }
    dft16_tail<SGN>(w, v);
}

// forward DFT16 with inputs 8..15 == 0 (zero-padded), SGN=-1
__device__ __forceinline__ void dft16_zero8(float2 v[16]){
    float2 w[16];
    #pragma unroll
    for (int n0 = 0; n0 < 4; ++n0){
        float2 a = v[n0], b = v[n0+4];
        w[n0]    = cadd(a,b);
        w[4+n0]  = make_float2(a.x + b.y, a.y - b.x);  // a - i b
        w[8+n0]  = csub(a,b);
        w[12+n0] = make_float2(a.x - b.y, a.y + b.x);  // a + i b
    }
    dft16_tail<-1>(w, v);
}

template<int SGN>
__device__ __forceinline__ void twchain16(float2 v[16], float theta){
    float th = (SGN < 0) ? -theta : theta;
    float s1,c1; __sincosf(th, &s1, &c1);
    float s4,c4; __sincosf(4.0f*th, &s4, &c4);
    float2 w1 = make_float2(c1,s1), w4 = make_float2(c4,s4);
    float2 lo2 = cmul(w1,w1), lo3 = cmul(lo2,w1);
    float2 hi2 = cmul(w4,w4), hi3 = cmul(hi2,w4);
    float2 lo[4] = {make_float2(1.f,0.f), w1, lo2, lo3};
    float2 hi[4] = {make_float2(1.f,0.f), w4, hi2, hi3};
    #pragma unroll
    for (int s = 1; s < 16; ++s){
        v[s] = cmul(v[s], cmul(hi[s>>2], lo[s&3]));
    }
}

__device__ __forceinline__ int L1swz(int e){
    return (e & ~63) | (((e & 63) + ((e >> 6) & 15)) & 63);
}

// Forward FFT: 32 blocks x 1024 threads, zero redundancy.
// Stage A: thread j = tid does one column (8 sincos + zero-padded DFT16 + tw).
// Stages B/C: wave wv = chunk wv (16 waves = 16 chunks), R6-verified maps.
// Spec stored as bf16x2 (u32 per complex), same element layout as R6.
__global__ __launch_bounds__(THREADS, 4) void fwd_fft_kernel(const float* __restrict__ x,
                                                             unsigned* __restrict__ spec) {
    __shared__ float2 X[FFT_N];  // 128 KiB
    const int m = blockIdx.x;
    const int tid = threadIdx.x;
    float2 v[16];

    // Stage A
    #pragma unroll
    for (int s = 0; s < 8; ++s){
        float ph = TWOPI_F * x[m*NLEN + s*1024 + tid];
        float sn,cs; __sincosf(ph,&sn,&cs);
        v[s] = make_float2(cs,sn);
    }
    dft16_zero8(v);
    twchain16<-1>(v, TWOPI_F * (float)tid / 16384.0f);
    #pragma unroll
    for (int s = 0; s < 16; ++s) X[s*1024 + L1swz(tid)] = v[s];
    __syncthreads();

    // Stage B: wave wv = chunk wv
    const int wv = tid >> 6, jB = tid & 63;
    #pragma unroll
    for (int t = 0; t < 16; ++t) v[t] = X[wv*1024 + t*64 + ((jB + t) & 63)];
    dft16<-1>(v);
    twchain16<-1>(v, TWOPI_F * (float)jB / 1024.0f);
    #pragma unroll
    for (int sp = 0; sp < 16; ++sp) X[wv*1024 + sp*64 + ((jB + 4*sp) & 63)] = v[sp];
    // no barrier: stage C reads only this wave's chunk

    // Stage C: DFT16 + tw W64 + 4-lane DPP DFT4, bf16 store
    {
        const int bl = (tid & 63) >> 2, jC = tid & 3;
        #pragma unroll
        for (int a = 0; a < 16; ++a)
            v[a] = X[wv*1024 + bl*64 + ((4*a + jC + 4*bl) & 63)];
        dft16<-1>(v);
        twchain16<-1>(v, TWOPI_F * (float)jC / 64.0f);
        const bool odd1 = (jC & 1) != 0;
        const bool odd2 = (jC & 2) != 0;
        #pragma unroll
        for (int e = 0; e < 16; ++e){
            float2 p = dpp_xor2(v[e]);
            float2 t = odd2 ? csub(p, v[e]) : cadd(v[e], p);
            float2 q = dpp_xor1(t);
            float2 re = odd1 ? csub(q, t) : cadd(t, q);
            float2 ro = odd1 ? cadd(q, mul_i(t)) : cadd(t, mul_mi(q));
            v[e] = odd2 ? ro : re;
        }
        const int u = ((jC & 1) << 1) | (jC >> 1);
        uint4* dst = (uint4*)(spec + (size_t)m*FFT_N + wv*1024 + bl*64 + u*16);
        #pragma unroll
        for (int e = 0; e < 4; ++e)
            dst[e] = make_uint4(pkc(v[4*e]), pkc(v[4*e+1]), pkc(v[4*e+2]), pkc(v[4*e+3]));
    }
}

// Pair kernel: R6-verified network, LDS+spec compressed to bf16x2 -> 64 KiB LDS,
// 2 blocks/CU. launch_bounds(1024,8) caps VGPR at 64 so both blocks fit.
__global__ __launch_bounds__(THREADS, 8) void pair_kernel(const unsigned* __restrict__ spec,
                                                          float4* __restrict__ rec) {
    __shared__ unsigned X[FFT_N];  // 64 KiB, bf16x2 per element
    const int r = blockIdx.x, tid = threadIdx.x;
    const bool is_auto = (r >= 496);
    int a, b, rec_idx;
    if (is_auto){
        a = b = r - 496;
        rec_idx = r - 496;           // autos -> rec[0..31]
    } else {
        int t = r; a = 0; int rem = M_WAVE - 1;
        while (t >= rem){ t -= rem; ++a; rem = M_WAVE - 1 - a; }
        b = a + 1 + t;
        rec_idx = M_WAVE + r;        // cross -> rec[32..527]
    }
    const int blk = tid >> 2, jC = tid & 3;
    const int u = ((jC & 1) << 1) | (jC >> 1);
    float2 v[16];

    // Load both spectra (bf16x2, 64 B contiguous each), product B*conj(A)
    {
        const uint4* pa = (const uint4*)(spec + (size_t)a*FFT_N + blk*64 + u*16);
        const uint4* pb = (const uint4*)(spec + (size_t)b*FFT_N + blk*64 + u*16);
        #pragma unroll
        for (int e = 0; e < 4; ++e){
            uint4 A = pa[e], B = pb[e];
            float2 a0 = upkc(A.x), a1 = upkc(A.y), a2 = upkc(A.z), a3 = upkc(A.w);
            float2 b0 = upkc(B.x), b1 = upkc(B.y), b2 = upkc(B.z), b3 = upkc(B.w);
            v[4*e+0] = make_float2(b0.x*a0.x + b0.y*a0.y, b0.y*a0.x - b0.x*a0.y);
            v[4*e+1] = make_float2(b1.x*a1.x + b1.y*a1.y, b1.y*a1.x - b1.x*a1.y);
            v[4*e+2] = make_float2(b2.x*a2.x + b2.y*a2.y, b2.y*a2.x - b2.x*a2.y);
            v[4*e+3] = make_float2(b3.x*a3.x + b3.y*a3.y, b3.y*a3.x - b3.x*a3.y);
        }
    }
    // Stage C': adjoint lane-DFT4, conj twiddle W64, DFT16^H, LDS write (bf16)
    {
        const bool odd1 = (jC & 1) != 0;
        const bool odd2 = (jC & 2) != 0;
        #pragma unroll
        for (int e = 0; e < 16; ++e){
            float2 q = dpp_xor1(v[e]);
            float2 t = odd1 ? csub(q, v[e]) : cadd(v[e], q);
            float2 p = dpp_xor2(t);
            float2 re = odd2 ? csub(p, t) : cadd(t, p);
            float2 ro = odd2 ? csub(p, mul_i(t)) : cadd(t, mul_i(p));
            v[e] = odd1 ? ro : re;
        }
        twchain16<+1>(v, TWOPI_F * (float)jC / 64.0f);
        dft16<+1>(v);
        const int rot = 4*(blk & 15);
        #pragma unroll
        for (int t = 0; t < 16; ++t) X[blk*64 + ((4*t + jC + rot) & 63)] = pkc(v[t]);
    }
    // no barrier: B' reads only this wave's chunk
    // Stage B'
    {
        const int sB = tid >> 6, jB = tid & 63;
        #pragma unroll
        for (int sp = 0; sp < 16; ++sp) v[sp] = upkc(X[sB*1024 + sp*64 + ((jB + 4*sp) & 63)]);
        twchain16<+1>(v, TWOPI_F * (float)jB / 1024.0f);
        dft16<+1>(v);
        #pragma unroll
        for (int t = 0; t < 16; ++t) X[sB*1024 + t*64 + ((jB + t) & 63)] = pkc(v[t]);
    }
    __syncthreads();   // cross-wave: A' gathers from all chunks
    // Stage A': v[t] = 16384 * sigma[t*1024 + tid]
    {
        const int baseA = L1swz(tid);
        #pragma unroll
        for (int s = 0; s < 16; ++s) v[s] = upkc(X[s*1024 + baseA]);
        twchain16<+1>(v, TWOPI_F * (float)tid / 16384.0f);
        dft16<+1>(v);
    }

    // Stats. Lags: auto uses n in [N+1, 2N-1]; cross uses all n except N, n=0 double.
    const float CSCALE = 0.1f / (16384.0f * 16384.0f);
    const bool j0 = (tid == 0);
    float uval[16];
    float lm = 0.f, lsum = 0.f;
    #pragma unroll
    for (int t = 0; t < 16; ++t){
        float uu = CSCALE * (v[t].x*v[t].x + v[t].y*v[t].y);
        uval[t] = uu;
        if (is_auto){
            bool valid = (t > 8) || ((t == 8) && !j0);
            if (valid){ lm = fmaxf(lm, uu); lsum += uu; }
        } else {
            bool inv = (t == 8) && j0;
            if (!inv){ lm = fmaxf(lm, uu); lsum += uu; }
            if (t == 0 && j0) lsum += uu;
        }
    }
    __syncthreads();  // X reads done; reuse as scratch

    float* scratch = (float*)X;
    const int lane = tid & 63, wvv = tid >> 6;
    float wm = waveReduceMax(lm);
    float wsm = waveReduceSum(lsum);
    if (lane == 0){ scratch[wvv] = wm; scratch[16+wvv] = wsm; }
    __syncthreads();
    float m_b = scratch[0], sumu = scratch[16];
    #pragma unroll
    for (int i = 1; i < 16; ++i){ m_b = fmaxf(m_b, scratch[i]); sumu += scratch[16+i]; }

    const float invTN2 = 1.0f / 67108.864f;   // 1/(T*N*N)
    float le = 0.f;
    #pragma unroll
    for (int t = 0; t < 16; ++t){
        float ex = __expf((uval[t] - m_b) * invTN2);
        if (is_auto){
            bool valid = (t > 8) || ((t == 8) && !j0);
            if (valid) le += ex;
        } else {
            bool inv = (t == 8) && j0;
            if (!inv) le += ((t == 0 && j0) ? 2.f : 1.f) * ex;
        }
    }
    float wle = waveReduceSum(le);
    if (lane == 0) scratch[32+wvv] = wle;
    __syncthreads();
    if (tid == 0){
        float sb2 = 0.f;
        #pragma unroll
        for (int i = 0; i < 16; ++i) sb2 += scratch[32+i];
        rec[rec_idx] = make_float4(m_b, sumu, sb2, 0.f);
    }
}

// Merge 528 records -> 7 outputs. Autos at rec[0..31], cross at rec[32..527].
__global__ __launch_bounds__(256) void final_kernel(const float4* __restrict__ rec,
                                                    float* __restrict__ out) {
    __shared__ float smA[256], smC[256];
    __shared__ double sS[256], sA[256], sC[256];
    const int tid = threadIdx.x;

    float mA = 0.f, mC = 0.f;
    for (int r = tid; r < NPAIR; r += 256){
        float mx = rec[r].x;
        if (r < M_WAVE) mA = fmaxf(mA, mx); else mC = fmaxf(mC, mx);
    }
    smA[tid] = mA; smC[tid] = mC;
    __syncthreads();
    for (int s = 128; s > 0; s >>= 1){
        if (tid < s){ smA[tid]=fmaxf(smA[tid],smA[tid+s]); smC[tid]=fmaxf(smC[tid],smC[tid+s]); }
        __syncthreads();
    }
    const float maxA_g = smA[0], maxC_g = smC[0];
    const float Mall = fmaxf(maxA_g, maxC_g);

    const float invTN2f = 1.0f / 67108.864f;
    double S = 0.0, sumA = 0.0, sumC = 0.0;
    for (int r = tid; r < NPAIR; r += 256){
        float4 rv = rec[r];
        S += (double)rv.z * (double)__expf((rv.x - Mall)*invTN2f);
        if (r < M_WAVE) sumA += (double)rv.y; else sumC += (double)rv.y;
    }
    sS[tid]=S; sA[tid]=sumA; sC[tid]=sumC;
    __syncthreads();
    for (int s = 128; s > 0; s >>= 1){
        if (tid < s){ sS[tid]+=sS[tid+s]; sA[tid]+=sA[tid+s]; sC[tid]+=sC[tid+s]; }
        __syncthreads();
    }
    if (tid == 0){
        const double invN2 = 1.0/67108864.0;
        out[0] = (float)((double)Mall*invN2 + 1e-3*log(sS[0]));
        out[1] = (float)((double)Mall*invN2);
        out[2] = maxA_g;
        out[3] = maxC_g;
        out[4] = (float)((sA[0]+sC[0])*invN2);
        out[5] = (float)sA[0];
        out[6] = (float)sC[0];
    }
}

extern "C" void kernel_launch(void* const* d_in, const int* in_sizes, int n_in,
                              void* d_out, int out_size, void* d_ws, size_t ws_size,
                              hipStream_t stream) {
    (void)in_sizes; (void)n_in; (void)out_size; (void)ws_size;
    const float* x = (const float*)d_in[0];
    float* out = (float*)d_out;

    unsigned* spec = (unsigned*)d_ws;   // 32*16384*4 B = 2 MiB (bf16x2)
    float4* rec = (float4*)((char*)d_ws + (size_t)M_WAVE * FFT_N * sizeof(unsigned));

    fwd_fft_kernel<<<M_WAVE, THREADS, 0, stream>>>(x, spec);
    pair_kernel<<<NPAIR, THREADS, 0, stream>>>(spec, rec);
    final_kernel<<<1, 256, 0, stream>>>(rec, out);
}